// Round 3
// baseline (3926.877 us; speedup 1.0000x reference)
//
#include <hip/hip_runtime.h>

#define E_N 100000
#define NV_N 50000
#define NG_N 2000

typedef short s8v __attribute__((ext_vector_type(8)));
typedef unsigned short u16x8 __attribute__((ext_vector_type(8)));
typedef float f32x4 __attribute__((ext_vector_type(4)));

__device__ __forceinline__ float bf2f(unsigned short u) {
  return __uint_as_float(((unsigned int)u) << 16);
}
__device__ __forceinline__ unsigned short f2bf(float f) {
  unsigned int u = __float_as_uint(f);
  u = u + 0x7fffu + ((u >> 16) & 1u);   // RNE
  return (unsigned short)(u >> 16);
}

// ---------------- precompute kernels ----------------

// tabs: [4][256][1024] bf16. tb0: W1a rows0-7 + b1a; tb1: rows8-15; tb2/tb3: W2a.
__global__ void k_tables(const float* __restrict__ W1a, const float* __restrict__ b1a,
                         const float* __restrict__ W2a, const float* __restrict__ b2a,
                         unsigned short* __restrict__ tabs) {
  int tid = blockIdx.x * 256 + threadIdx.x;
  int tb = tid >> 18, v = (tid >> 10) & 255, k = tid & 1023;
  const float* W = (tb < 2) ? W1a : W2a;
  int rbase = (tb & 1) ? 8 : 0;
  float s = 0.f;
  if ((tb & 1) == 0) s = (tb < 2) ? b1a[k] : b2a[k];
  #pragma unroll
  for (int j = 0; j < 8; ++j)
    if ((v >> (7 - j)) & 1) s += W[(rbase + j) * 1024 + k];
  tabs[tid] = f2bf(s);
}

// dst[n*1024 + k] = bf16(src[k*N + n]) ; K=1024, N mult of 32
__global__ void k_transpose(const float* __restrict__ src, unsigned short* __restrict__ dst,
                            int K, int N) {
  __shared__ float tile[32][33];
  int ntx = N >> 5;
  int tk = blockIdx.x / ntx, tn = blockIdx.x - tk * ntx;
  int k0 = tk * 32, n0 = tn * 32;
  int lx = threadIdx.x & 31, ly = threadIdx.x >> 5;
  #pragma unroll
  for (int yy = ly; yy < 32; yy += 8)
    tile[yy][lx] = src[(k0 + yy) * N + (n0 + lx)];
  __syncthreads();
  #pragma unroll
  for (int yy = ly; yy < 32; yy += 8)
    dst[(size_t)(n0 + yy) * 1024 + (k0 + lx)] = f2bf(tile[lx][yy]);
}

__global__ void k_count(const int* __restrict__ ei, int* __restrict__ cnt) {
  int e = blockIdx.x * 256 + threadIdx.x;
  if (e < E_N) atomicAdd(&cnt[ei[E_N + e]], 1);
}

// ---------------- fused edge NNConv kernel ----------------
// 256 thr (4 waves), 64 edges/block. A (hidden) built per-128-K-chunk in LDS
// (2 barriers/chunk); B loaded per-lane global->VGPR fragments, software-
// pipelined one 32-K stage ahead. No barriers or LDS in the stage loop.
// Per-lane msg ownership -> direct global atomics.
template<int NCOLS, int FOUT>
__global__ void __launch_bounds__(256, 3)
k_edge(const float* __restrict__ xsrc, const int* __restrict__ ei,
       const int* __restrict__ eap,
       const unsigned short* __restrict__ tab0,
       const unsigned short* __restrict__ tab1,
       const unsigned short* __restrict__ WT,     // [NCOLS][1024] bf16
       const float* __restrict__ bvec,            // theta bias [NCOLS] fp32
       float* __restrict__ agg)                   // [NV][FOUT] fp32, pre-zeroed
{
  constexpr int NC = NCOLS / 256;                 // 256-col slices
  constexpr int K1 = (FOUT == 64) ? 64 : 32;      // nf col stride

  __shared__ unsigned short sHid[64 * 128];       // 16KB, swizzled kb^(m&15)
  __shared__ float sXf[64 * 36];                  // 9KB fp32 x rows (pad 36)
  __shared__ int sSrc[64], sDst[64];
  __shared__ unsigned char sb0[64], sb1[64];

  const int t = threadIdx.x;
  const int l = t & 63;
  const int wc = t >> 6;            // 0..3
  const int lg = l >> 4;            // 0..3
  const int ll = l & 15;
  const int e0 = blockIdx.x * 64;
  const int c0 = (FOUT == 64) ? wc * 16 : ((wc >> 1) * 128 + (wc & 1) * 16);

  // ---- per-lane B fragment load: stage s = 4*nc + ks within chunk q ----
  auto loadB = [&](s8v* bv, int q, int s) {
    int nc = s >> 2, ks = s & 3;
    const unsigned short* p =
        WT + (size_t)(nc * 256 + c0 + ll) * 1024 + q * 128 + ks * 32 + lg * 8;
    #pragma unroll
    for (int nf = 0; nf < 4; ++nf)
      bv[nf] = *(const s8v*)(p + (size_t)nf * K1 * 1024);
  };

  auto loadA = [&](s8v* av, int ks) {
    #pragma unroll
    for (int mf = 0; mf < 4; ++mf) {
      int row = mf * 16 + ll;
      int kb = ks * 4 + lg;
      av[mf] = *(const s8v*)&sHid[row * 128 + 8 * (kb ^ (row & 15))];
    }
  };

  // ---- build hidden chunk q (k in [q*128, q*128+128)) into sHid ----
  auto build = [&](int q) {
    int m = t >> 2, kq = (t & 3) * 32;
    const unsigned short* p0 = tab0 + (size_t)sb0[m] * 1024 + q * 128 + kq;
    const unsigned short* p1 = tab1 + (size_t)sb1[m] * 1024 + q * 128 + kq;
    #pragma unroll
    for (int j = 0; j < 4; ++j) {
      u16x8 a = *(const u16x8*)(p0 + j * 8);
      u16x8 b = *(const u16x8*)(p1 + j * 8);
      u16x8 h;
      #pragma unroll
      for (int u = 0; u < 8; ++u)
        h[u] = f2bf(fmaxf(bf2f(a[u]) + bf2f(b[u]), 0.f));
      int kb = (t & 3) * 4 + j;
      *(u16x8*)&sHid[m * 128 + 8 * (kb ^ (m & 15))] = h;
    }
  };

  // ---- prologue ----
  s8v bvA[4], bvB[4];
  loadB(bvA, 0, 0);                 // earliest possible issue
  if (t < 64) {
    int e = e0 + t;
    if (e < E_N) {
      sSrc[t] = ei[e]; sDst[t] = ei[E_N + e];
      sb0[t] = (unsigned char)(eap[2 * e] & 255);
      sb1[t] = (unsigned char)(eap[2 * e + 1] & 255);
    } else { sSrc[t] = 0; sDst[t] = -1; sb0[t] = 0; sb1[t] = 0; }
  }
  __syncthreads();
  for (int j = t; j < 64 * 32; j += 256) {
    int m = j >> 5, i = j & 31;
    sXf[m * 36 + i] = (e0 + m < E_N) ? xsrc[(size_t)sSrc[m] * 32 + i] : 0.f;
  }
  build(0);
  __syncthreads();

  float msgr[4][4] = {};

  for (int q = 0; q < 8; ++q) {
    if (q > 0) {
      __syncthreads();              // all reads of prev chunk done
      build(q);
      __syncthreads();
    }
    for (int nc = 0; nc < NC; ++nc) {
      f32x4 acc[4][4];
      s8v av[4];
      // ks = 0 (zero-init accumulate)
      loadB(bvB, q, 4 * nc + 1);
      loadA(av, 0);
      __builtin_amdgcn_s_setprio(1);
      #pragma unroll
      for (int mf = 0; mf < 4; ++mf)
        #pragma unroll
        for (int nf = 0; nf < 4; ++nf)
          acc[mf][nf] = __builtin_amdgcn_mfma_f32_16x16x32_bf16(
              av[mf], bvA[nf], (f32x4){0.f, 0.f, 0.f, 0.f}, 0, 0, 0);
      __builtin_amdgcn_s_setprio(0);
      // ks = 1
      loadB(bvA, q, 4 * nc + 2);
      loadA(av, 1);
      __builtin_amdgcn_s_setprio(1);
      #pragma unroll
      for (int mf = 0; mf < 4; ++mf)
        #pragma unroll
        for (int nf = 0; nf < 4; ++nf)
          acc[mf][nf] = __builtin_amdgcn_mfma_f32_16x16x32_bf16(av[mf], bvB[nf], acc[mf][nf], 0, 0, 0);
      __builtin_amdgcn_s_setprio(0);
      // ks = 2
      loadB(bvB, q, 4 * nc + 3);
      loadA(av, 2);
      __builtin_amdgcn_s_setprio(1);
      #pragma unroll
      for (int mf = 0; mf < 4; ++mf)
        #pragma unroll
        for (int nf = 0; nf < 4; ++nf)
          acc[mf][nf] = __builtin_amdgcn_mfma_f32_16x16x32_bf16(av[mf], bvA[nf], acc[mf][nf], 0, 0, 0);
      __builtin_amdgcn_s_setprio(0);
      // ks = 3 (+ prefetch next nc / next q stage 0)
      if (nc + 1 < NC) loadB(bvA, q, 4 * nc + 4);
      else if (q < 7) loadB(bvA, q + 1, 0);
      loadA(av, 3);
      __builtin_amdgcn_s_setprio(1);
      #pragma unroll
      for (int mf = 0; mf < 4; ++mf)
        #pragma unroll
        for (int nf = 0; nf < 4; ++nf)
          acc[mf][nf] = __builtin_amdgcn_mfma_f32_16x16x32_bf16(av[mf], bvB[nf], acc[mf][nf], 0, 0, 0);
      __builtin_amdgcn_s_setprio(0);

      // contract partial theta into per-lane msg (linearity over K)
      const int i0 = (FOUT == 64) ? nc * 4 : nc * 8 + (wc >> 1) * 4;
      #pragma unroll
      for (int mf = 0; mf < 4; ++mf) {
        #pragma unroll
        for (int r = 0; r < 4; ++r) {
          int row = mf * 16 + lg * 4 + r;
          f32x4 xv = *(const f32x4*)&sXf[row * 36 + i0];
          #pragma unroll
          for (int nf = 0; nf < 4; ++nf)
            msgr[mf][r] += acc[mf][nf][r] * xv[nf];
        }
      }
    }
  }

  // ---- bias term: theta_bias[:, n] = bvec[n] (no MFMA needed) ----
  for (int nc = 0; nc < NC; ++nc) {
    float bb[4];
    #pragma unroll
    for (int nf = 0; nf < 4; ++nf)
      bb[nf] = bvec[nc * 256 + c0 + ll + nf * K1];
    const int i0 = (FOUT == 64) ? nc * 4 : nc * 8 + (wc >> 1) * 4;
    #pragma unroll
    for (int mf = 0; mf < 4; ++mf) {
      #pragma unroll
      for (int r = 0; r < 4; ++r) {
        int row = mf * 16 + lg * 4 + r;
        f32x4 xv = *(const f32x4*)&sXf[row * 36 + i0];
        #pragma unroll
        for (int nf = 0; nf < 4; ++nf)
          msgr[mf][r] += bb[nf] * xv[nf];
      }
    }
  }

  // ---- epilogue: lane owns (row, o); scatter to agg[dst] ----
  const int o = ((FOUT == 64) ? wc * 16 : (wc & 1) * 16) + ll;
  #pragma unroll
  for (int mf = 0; mf < 4; ++mf)
    #pragma unroll
    for (int r = 0; r < 4; ++r) {
      int row = mf * 16 + lg * 4 + r;
      int d = sDst[row];
      if (d >= 0) atomicAdd(&agg[(size_t)d * FOUT + o], msgr[mf][r]);
    }
}

// ---------------- node update / pool / MLP ----------------

__global__ void k_node1(const float* __restrict__ x, const float* __restrict__ agg,
                        const int* __restrict__ cnt, const float* __restrict__ root,
                        const float* __restrict__ bias, float* __restrict__ h) {
  int tid = blockIdx.x * 256 + threadIdx.x;
  if (tid >= NV_N * 32) return;
  int n = tid >> 5, j = tid & 31;
  const float* xr = x + n * 32;
  float s = 0.f;
  #pragma unroll
  for (int i = 0; i < 32; ++i) s = fmaf(xr[i], root[i * 32 + j], s);
  int c = cnt[n]; if (c < 1) c = 1;
  h[tid] = fmaxf(agg[tid] / (float)c + s + bias[j], 0.f);
}

__global__ void k_node2(const float* __restrict__ hin, const float* __restrict__ agg,
                        const int* __restrict__ cnt, const float* __restrict__ root,
                        const float* __restrict__ bias, float* __restrict__ h2) {
  int tid = blockIdx.x * 256 + threadIdx.x;
  if (tid >= NV_N * 64) return;
  int n = tid >> 6, j = tid & 63;
  const float* xr = hin + n * 32;
  float s = 0.f;
  #pragma unroll
  for (int i = 0; i < 32; ++i) s = fmaf(xr[i], root[i * 64 + j], s);
  int c = cnt[n]; if (c < 1) c = 1;
  h2[tid] = fmaxf(agg[tid] / (float)c + s + bias[j], 0.f);
}

__device__ __forceinline__ int lowerb(const int* __restrict__ a, int n, int key) {
  int lo = 0, hi = n;
  while (lo < hi) { int mid = (lo + hi) >> 1; if (a[mid] < key) lo = mid + 1; else hi = mid; }
  return lo;
}

__global__ void k_pool(const float* __restrict__ h2, const int* __restrict__ batch,
                       float* __restrict__ g) {
  int gid = (blockIdx.x * 256 + threadIdx.x) >> 6;
  int l = threadIdx.x & 63;
  if (gid >= NG_N) return;
  int lo = lowerb(batch, NV_N, gid);
  int hi = lowerb(batch, NV_N, gid + 1);
  float s = 0.f;
  for (int n = lo; n < hi; ++n) s += h2[n * 64 + l];
  int c = hi - lo; if (c < 1) c = 1;
  g[gid * 64 + l] = s / (float)c;
}

template<int K, bool RELU>
__global__ void k_fc(const float* __restrict__ A, const float* __restrict__ W,
                     const float* __restrict__ bias, float* __restrict__ out, int N) {
  __shared__ float sA[8][K];
  int r0 = blockIdx.x * 8;
  int n = blockIdx.y * 256 + threadIdx.x;
  for (int j = threadIdx.x; j < 8 * K; j += 256) {
    int rr = j / K, kk = j - rr * K;
    int r = r0 + rr;
    sA[rr][kk] = (r < NG_N) ? A[r * K + kk] : 0.f;
  }
  __syncthreads();
  float acc[8] = {0.f, 0.f, 0.f, 0.f, 0.f, 0.f, 0.f, 0.f};
  for (int k = 0; k < K; ++k) {
    float b = W[k * N + n];
    #pragma unroll
    for (int rr = 0; rr < 8; ++rr) acc[rr] = fmaf(sA[rr][k], b, acc[rr]);
  }
  float bs = bias[n];
  #pragma unroll
  for (int rr = 0; rr < 8; ++rr) {
    int r = r0 + rr;
    if (r < NG_N) {
      float v = acc[rr] + bs;
      if (RELU) v = fmaxf(v, 0.f);
      out[r * N + n] = v;
    }
  }
}

__global__ void k_fc4(const float* __restrict__ A, const float* __restrict__ W,
                      const float* __restrict__ bias, float* __restrict__ out) {
  int tid = blockIdx.x * 256 + threadIdx.x;
  int r = tid >> 2, s = tid & 3;
  if (r >= NG_N || s >= 3) return;
  float acc = bias[s];
  for (int k = 0; k < 256; ++k) acc = fmaf(A[r * 256 + k], W[k * 3 + s], acc);
  out[r * 3 + s] = acc;
}

// ---------------- launch ----------------

extern "C" void kernel_launch(void* const* d_in, const int* in_sizes, int n_in,
                              void* d_out, int out_size, void* d_ws, size_t ws_size,
                              hipStream_t stream) {
  const float* x     = (const float*)d_in[0];
  const int*   ei    = (const int*)d_in[1];
  const int*   eap   = (const int*)d_in[2];
  const int*   batch = (const int*)d_in[3];
  const float* W1a   = (const float*)d_in[4];
  const float* b1a   = (const float*)d_in[5];
  const float* W1b   = (const float*)d_in[6];
  const float* b1b   = (const float*)d_in[7];
  const float* W2a   = (const float*)d_in[8];
  const float* b2a   = (const float*)d_in[9];
  const float* W2b   = (const float*)d_in[10];
  const float* b2b   = (const float*)d_in[11];
  const float* root1 = (const float*)d_in[12];
  const float* bias1 = (const float*)d_in[13];
  const float* root2 = (const float*)d_in[14];
  const float* bias2 = (const float*)d_in[15];
  const float* fcW1  = (const float*)d_in[16];
  const float* fcb1  = (const float*)d_in[17];
  const float* fcW2  = (const float*)d_in[18];
  const float* fcb2  = (const float*)d_in[19];
  const float* fcW3  = (const float*)d_in[20];
  const float* fcb3  = (const float*)d_in[21];
  const float* fcW4  = (const float*)d_in[22];
  const float* fcb4  = (const float*)d_in[23];
  float* out = (float*)d_out;

  char* w = (char*)d_ws;
  size_t off = 0;
  auto take = [&](size_t bytes) -> void* {
    void* p = w + off;
    off = (off + bytes + 255) & ~(size_t)255;
    return p;
  };
  unsigned short* tabs = (unsigned short*)take(4 * 256 * 1024 * 2);
  unsigned short* w1t  = (unsigned short*)take((size_t)1024 * 1024 * 2);
  unsigned short* w2t  = (unsigned short*)take((size_t)2048 * 1024 * 2);
  float* agg1 = (float*)take((size_t)NV_N * 32 * 4);
  float* agg2 = (float*)take((size_t)NV_N * 64 * 4);
  int*   cnt  = (int*)take((size_t)NV_N * 4);
  float* h    = (float*)take((size_t)NV_N * 32 * 4);
  float* h2   = (float*)take((size_t)NV_N * 64 * 4);
  float* g    = (float*)take((size_t)NG_N * 64 * 4);
  float* l1   = (float*)take((size_t)NG_N * 512 * 4);
  float* l2   = (float*)take((size_t)NG_N * 512 * 4);
  float* l3   = (float*)take((size_t)NG_N * 256 * 4);

  hipMemsetAsync(agg1, 0, (size_t)NV_N * 32 * 4, stream);
  hipMemsetAsync(agg2, 0, (size_t)NV_N * 64 * 4, stream);
  hipMemsetAsync(cnt, 0, (size_t)NV_N * 4, stream);

  k_tables<<<4096, 256, 0, stream>>>(W1a, b1a, W2a, b2a, tabs);
  k_transpose<<<(1024 / 32) * (1024 / 32), 256, 0, stream>>>(W1b, w1t, 1024, 1024);
  k_transpose<<<(1024 / 32) * (2048 / 32), 256, 0, stream>>>(W2b, w2t, 1024, 2048);
  k_count<<<(E_N + 255) / 256, 256, 0, stream>>>(ei, cnt);

  const int nblk = (E_N + 63) / 64;
  k_edge<1024, 32><<<nblk, 256, 0, stream>>>(x, ei, eap, tabs, tabs + 262144,
                                             w1t, b1b, agg1);
  k_node1<<<(NV_N * 32) / 256, 256, 0, stream>>>(x, agg1, cnt, root1, bias1, h);

  k_edge<2048, 64><<<nblk, 256, 0, stream>>>(h, ei, eap, tabs + 2 * 262144, tabs + 3 * 262144,
                                             w2t, b2b, agg2);
  k_node2<<<(NV_N * 64) / 256, 256, 0, stream>>>(h, agg2, cnt, root2, bias2, h2);

  k_pool<<<(NG_N * 64) / 256, 256, 0, stream>>>(h2, batch, g);

  k_fc<64, true><<<dim3((NG_N + 7) / 8, 2), 256, 0, stream>>>(g, fcW1, fcb1, l1, 512);
  k_fc<512, true><<<dim3((NG_N + 7) / 8, 2), 256, 0, stream>>>(l1, fcW2, fcb2, l2, 512);
  k_fc<512, true><<<dim3((NG_N + 7) / 8, 1), 256, 0, stream>>>(l2, fcW3, fcb3, l3, 256);
  k_fc4<<<(NG_N * 4 + 255) / 256, 256, 0, stream>>>(l3, fcW4, fcb4, out);
}

// Round 5
// 993.107 us; speedup vs baseline: 3.9541x; 3.9541x over previous
//
#include <hip/hip_runtime.h>

#define E_N 100000
#define NV_N 50000
#define NG_N 2000

typedef short s8v __attribute__((ext_vector_type(8)));
typedef unsigned short u16x8 __attribute__((ext_vector_type(8)));
typedef float f32x4 __attribute__((ext_vector_type(4)));

__device__ __forceinline__ float bf2f(unsigned short u) {
  return __uint_as_float(((unsigned int)u) << 16);
}
__device__ __forceinline__ unsigned short f2bf(float f) {
  unsigned int u = __float_as_uint(f);
  u = u + 0x7fffu + ((u >> 16) & 1u);   // RNE
  return (unsigned short)(u >> 16);
}

// ---------------- precompute kernels ----------------

// tabs: [4][256][1024] bf16. tb0: W1a rows0-7 + b1a; tb1: rows8-15; tb2/tb3: W2a.
__global__ void k_tables(const float* __restrict__ W1a, const float* __restrict__ b1a,
                         const float* __restrict__ W2a, const float* __restrict__ b2a,
                         unsigned short* __restrict__ tabs) {
  int tid = blockIdx.x * 256 + threadIdx.x;
  int tb = tid >> 18, v = (tid >> 10) & 255, k = tid & 1023;
  const float* W = (tb < 2) ? W1a : W2a;
  int rbase = (tb & 1) ? 8 : 0;
  float s = 0.f;
  if ((tb & 1) == 0) s = (tb < 2) ? b1a[k] : b2a[k];
  #pragma unroll
  for (int j = 0; j < 8; ++j)
    if ((v >> (7 - j)) & 1) s += W[(rbase + j) * 1024 + k];
  tabs[tid] = f2bf(s);
}

// Pack W[k][n] (K=1024, fp32) into MFMA-fragment streaming order:
// frag fi = ((q*(N/32) + cb)*2 + ks)*2 + nf ; within frag, vec r = lg*16+ll
// holds k = q*64+ks*32+lg*8+u, n = cb*32+nf*16+ll. Each frag = 1KB contiguous.
__global__ void k_pack(const float* __restrict__ src, unsigned short* __restrict__ dst, int N) {
  int tid = blockIdx.x * 256 + threadIdx.x;
  int total = (1024 / 8) * N;
  if (tid >= total) return;
  int fi = tid >> 6, r = tid & 63;
  int lg = r >> 4, ll = r & 15;
  int nf = fi & 1, ks = (fi >> 1) & 1;
  int rest = fi >> 2;
  int nc32 = N / 32;
  int cb = rest % nc32, q = rest / nc32;
  int k0 = q * 64 + ks * 32 + lg * 8;
  int n = cb * 32 + nf * 16 + ll;
  u16x8 v;
  #pragma unroll
  for (int u = 0; u < 8; ++u)
    v[u] = f2bf(src[(size_t)(k0 + u) * N + n]);
  *(u16x8*)&dst[(size_t)tid * 8] = v;
}

__global__ void k_count(const int* __restrict__ ei, int* __restrict__ cnt) {
  int e = blockIdx.x * 256 + threadIdx.x;
  if (e < E_N) atomicAdd(&cnt[ei[E_N + e]], 1);
}

// ---------------- fused edge NNConv kernel ----------------
// 256 thr = 4 waves (2 row-halves x 2 col-halves), 128 edges/block.
// K-chunk KC=64: hidden built in LDS (2 barriers/chunk), A-frags hoisted to
// regs once per chunk; B read per-lane from packed array (coalesced 1KB frags,
// convoy L2 locality), double-buffered, barrier-free K-loop.
// Ownership map: FOUT=64 -> wave (wr,wc) owns rows [wr*64,+64) x o in
// [wc*32,+32) exclusively. FOUT=32 -> (row,o) owned by BOTH wc waves, which
// split the i-dimension by parity (i = np*2+wc); bias must follow that split.
template<int NCOLS, int FOUT>
__global__ void __launch_bounds__(256, 4)
k_edge(const float* __restrict__ xsrc, const int* __restrict__ ei,
       const int* __restrict__ eap,
       const unsigned short* __restrict__ tab0,
       const unsigned short* __restrict__ tab1,
       const unsigned short* __restrict__ WP,     // packed B
       const float* __restrict__ bvec,            // theta bias [NCOLS] fp32
       float* __restrict__ agg)                   // [NV][FOUT] fp32, pre-zeroed
{
  constexpr int NP = NCOLS / 64;                  // npasses per K-chunk

  __shared__ unsigned short sHid[128 * 64];       // 16KB, swizzled kb^(row&7)
  __shared__ float sXf[128 * 36];                 // 18KB fp32 x rows (pad 36)
  __shared__ int sSrc[128], sDst[128];
  __shared__ unsigned char sb0[128], sb1[128];

  const int t = threadIdx.x;
  const int l = t & 63;
  const int wid = t >> 6;
  const int wr = wid >> 1;          // 0..1 row half
  const int wc = wid & 1;           // 0..1 col half
  const int lg = l >> 4;            // 0..3
  const int ll = l & 15;
  const int e0 = blockIdx.x * 128;

  // per-lane packed-B fragment pair load (nf=0,1), contiguous 16B/lane
  auto loadB = [&](s8v* bv, int q, int np, int ks) {
    int fi = (((q * (NCOLS / 32) + np * 2 + wc) * 2 + ks) * 2);
    const unsigned short* p = WP + (size_t)fi * 512 + (size_t)l * 8;
    bv[0] = *(const s8v*)p;
    bv[1] = *(const s8v*)(p + 512);
  };

  // build hidden chunk q (k in [q*64, q*64+64)) into sHid
  auto build = [&](int q) {
    int m = t >> 1;
    const unsigned short* p0 = tab0 + (size_t)sb0[m] * 1024 + q * 64 + (t & 1) * 32;
    const unsigned short* p1 = tab1 + (size_t)sb1[m] * 1024 + q * 64 + (t & 1) * 32;
    #pragma unroll
    for (int j = 0; j < 4; ++j) {
      u16x8 a = *(const u16x8*)(p0 + j * 8);
      u16x8 b = *(const u16x8*)(p1 + j * 8);
      u16x8 h;
      #pragma unroll
      for (int u = 0; u < 8; ++u)
        h[u] = f2bf(fmaxf(bf2f(a[u]) + bf2f(b[u]), 0.f));
      int kb = (t & 1) * 4 + j;
      *(u16x8*)&sHid[m * 64 + 8 * (kb ^ (m & 7))] = h;
    }
  };

  // ---- prologue ----
  s8v bA[2], bB[2];
  loadB(bA, 0, 0, 0);
  loadB(bB, 0, 0, 1);
  if (t < 128) {
    int e = e0 + t;
    if (e < E_N) {
      sSrc[t] = ei[e]; sDst[t] = ei[E_N + e];
      sb0[t] = (unsigned char)(eap[2 * e] & 255);
      sb1[t] = (unsigned char)(eap[2 * e + 1] & 255);
    } else { sSrc[t] = 0; sDst[t] = -1; sb0[t] = 0; sb1[t] = 0; }
  }
  __syncthreads();
  for (int j = t; j < 128 * 32; j += 256) {
    int m = j >> 5, i = j & 31;
    sXf[m * 36 + i] = (e0 + m < E_N) ? xsrc[(size_t)sSrc[m] * 32 + i] : 0.f;
  }
  build(0);
  __syncthreads();

  float msgr[4][4][2] = {};

  for (int q = 0; q < 16; ++q) {
    if (q > 0) {
      __syncthreads();              // all prior sHid reads done
      build(q);
      __syncthreads();
    }
    // hoist A fragments for the whole chunk (reused across all npasses)
    s8v av[4][2];
    #pragma unroll
    for (int mf = 0; mf < 4; ++mf) {
      int row = wr * 64 + mf * 16 + ll;
      #pragma unroll
      for (int ks = 0; ks < 2; ++ks) {
        int kb = ks * 4 + lg;
        av[mf][ks] = *(const s8v*)&sHid[row * 64 + 8 * (kb ^ (row & 7))];
      }
    }
    for (int np = 0; np < NP; ++np) {
      int nq = q, nnp = np + 1;
      if (nnp == NP) { nnp = 0; nq = q + 1; }
      if (nq == 16) { nq = 15; nnp = 0; }          // tail: dummy reload
      f32x4 acc[4][2];
      // ks = 0
      #pragma unroll
      for (int mf = 0; mf < 4; ++mf)
        #pragma unroll
        for (int nf = 0; nf < 2; ++nf)
          acc[mf][nf] = __builtin_amdgcn_mfma_f32_16x16x32_bf16(
              av[mf][0], bA[nf], (f32x4){0.f, 0.f, 0.f, 0.f}, 0, 0, 0);
      loadB(bA, nq, nnp, 0);
      // ks = 1
      #pragma unroll
      for (int mf = 0; mf < 4; ++mf)
        #pragma unroll
        for (int nf = 0; nf < 2; ++nf)
          acc[mf][nf] = __builtin_amdgcn_mfma_f32_16x16x32_bf16(
              av[mf][1], bB[nf], acc[mf][nf], 0, 0, 0);
      loadB(bB, nq, nnp, 1);
      // contract partial theta into per-lane msg (linearity over K)
      const int iidx = (FOUT == 64) ? np : np * 2 + wc;
      #pragma unroll
      for (int mf = 0; mf < 4; ++mf) {
        #pragma unroll
        for (int r = 0; r < 4; ++r) {
          int row = wr * 64 + mf * 16 + lg * 4 + r;
          float xv = sXf[row * 36 + iidx];
          #pragma unroll
          for (int nf = 0; nf < 2; ++nf)
            msgr[mf][r][nf] += acc[mf][nf][r] * xv;
        }
      }
    }
  }

  // ---- bias term: msg += x @ reshape(bvec) ----
  // FOUT=32: (row,o) is co-owned by wc=0 and wc=1 -> split i by parity
  // (i%2 == wc), matching the GEMM's i-ownership. FOUT=64: exclusive o
  // ownership -> every wave adds its full i-sum.
  #pragma unroll 4
  for (int i = 0; i < 32; ++i) {
    if (FOUT == 32 && (i & 1) != wc) continue;
    float w[2];
    #pragma unroll
    for (int nf = 0; nf < 2; ++nf) {
      int o = ((FOUT == 64) ? (wc * 2 + nf) * 16 : nf * 16) + ll;
      w[nf] = bvec[i * FOUT + o];
    }
    #pragma unroll
    for (int mf = 0; mf < 4; ++mf)
      #pragma unroll
      for (int r = 0; r < 4; ++r) {
        int row = wr * 64 + mf * 16 + lg * 4 + r;
        float xv = sXf[row * 36 + i];
        msgr[mf][r][0] += xv * w[0];
        msgr[mf][r][1] += xv * w[1];
      }
  }

  // ---- epilogue: lane owns (row, o) pairs; scatter to agg[dst] ----
  #pragma unroll
  for (int nf = 0; nf < 2; ++nf) {
    const int o = ((FOUT == 64) ? (wc * 2 + nf) * 16 : nf * 16) + ll;
    #pragma unroll
    for (int mf = 0; mf < 4; ++mf)
      #pragma unroll
      for (int r = 0; r < 4; ++r) {
        int row = wr * 64 + mf * 16 + lg * 4 + r;
        int d = sDst[row];
        if (d >= 0) atomicAdd(&agg[(size_t)d * FOUT + o], msgr[mf][r][nf]);
      }
  }
}

// ---------------- node update / pool / MLP ----------------

__global__ void k_node1(const float* __restrict__ x, const float* __restrict__ agg,
                        const int* __restrict__ cnt, const float* __restrict__ root,
                        const float* __restrict__ bias, float* __restrict__ h) {
  int tid = blockIdx.x * 256 + threadIdx.x;
  if (tid >= NV_N * 32) return;
  int n = tid >> 5, j = tid & 31;
  const float* xr = x + n * 32;
  float s = 0.f;
  #pragma unroll
  for (int i = 0; i < 32; ++i) s = fmaf(xr[i], root[i * 32 + j], s);
  int c = cnt[n]; if (c < 1) c = 1;
  h[tid] = fmaxf(agg[tid] / (float)c + s + bias[j], 0.f);
}

__global__ void k_node2(const float* __restrict__ hin, const float* __restrict__ agg,
                        const int* __restrict__ cnt, const float* __restrict__ root,
                        const float* __restrict__ bias, float* __restrict__ h2) {
  int tid = blockIdx.x * 256 + threadIdx.x;
  if (tid >= NV_N * 64) return;
  int n = tid >> 6, j = tid & 63;
  const float* xr = hin + n * 32;
  float s = 0.f;
  #pragma unroll
  for (int i = 0; i < 32; ++i) s = fmaf(xr[i], root[i * 64 + j], s);
  int c = cnt[n]; if (c < 1) c = 1;
  h2[tid] = fmaxf(agg[tid] / (float)c + s + bias[j], 0.f);
}

__device__ __forceinline__ int lowerb(const int* __restrict__ a, int n, int key) {
  int lo = 0, hi = n;
  while (lo < hi) { int mid = (lo + hi) >> 1; if (a[mid] < key) lo = mid + 1; else hi = mid; }
  return lo;
}

__global__ void k_pool(const float* __restrict__ h2, const int* __restrict__ batch,
                       float* __restrict__ g) {
  int gid = (blockIdx.x * 256 + threadIdx.x) >> 6;
  int l = threadIdx.x & 63;
  if (gid >= NG_N) return;
  int lo = lowerb(batch, NV_N, gid);
  int hi = lowerb(batch, NV_N, gid + 1);
  float s = 0.f;
  for (int n = lo; n < hi; ++n) s += h2[n * 64 + l];
  int c = hi - lo; if (c < 1) c = 1;
  g[gid * 64 + l] = s / (float)c;
}

template<int K, bool RELU>
__global__ void k_fc(const float* __restrict__ A, const float* __restrict__ W,
                     const float* __restrict__ bias, float* __restrict__ out, int N) {
  __shared__ float sA[8][K];
  int r0 = blockIdx.x * 8;
  int n = blockIdx.y * 256 + threadIdx.x;
  for (int j = threadIdx.x; j < 8 * K; j += 256) {
    int rr = j / K, kk = j - rr * K;
    int r = r0 + rr;
    sA[rr][kk] = (r < NG_N) ? A[r * K + kk] : 0.f;
  }
  __syncthreads();
  float acc[8] = {0.f, 0.f, 0.f, 0.f, 0.f, 0.f, 0.f, 0.f};
  for (int k = 0; k < K; ++k) {
    float b = W[k * N + n];
    #pragma unroll
    for (int rr = 0; rr < 8; ++rr) acc[rr] = fmaf(sA[rr][k], b, acc[rr]);
  }
  float bs = bias[n];
  #pragma unroll
  for (int rr = 0; rr < 8; ++rr) {
    int r = r0 + rr;
    if (r < NG_N) {
      float v = acc[rr] + bs;
      if (RELU) v = fmaxf(v, 0.f);
      out[r * N + n] = v;
    }
  }
}

__global__ void k_fc4(const float* __restrict__ A, const float* __restrict__ W,
                      const float* __restrict__ bias, float* __restrict__ out) {
  int tid = blockIdx.x * 256 + threadIdx.x;
  int r = tid >> 2, s = tid & 3;
  if (r >= NG_N || s >= 3) return;
  float acc = bias[s];
  for (int k = 0; k < 256; ++k) acc = fmaf(A[r * 256 + k], W[k * 3 + s], acc);
  out[r * 3 + s] = acc;
}

// ---------------- launch ----------------

extern "C" void kernel_launch(void* const* d_in, const int* in_sizes, int n_in,
                              void* d_out, int out_size, void* d_ws, size_t ws_size,
                              hipStream_t stream) {
  const float* x     = (const float*)d_in[0];
  const int*   ei    = (const int*)d_in[1];
  const int*   eap   = (const int*)d_in[2];
  const int*   batch = (const int*)d_in[3];
  const float* W1a   = (const float*)d_in[4];
  const float* b1a   = (const float*)d_in[5];
  const float* W1b   = (const float*)d_in[6];
  const float* b1b   = (const float*)d_in[7];
  const float* W2a   = (const float*)d_in[8];
  const float* b2a   = (const float*)d_in[9];
  const float* W2b   = (const float*)d_in[10];
  const float* b2b   = (const float*)d_in[11];
  const float* root1 = (const float*)d_in[12];
  const float* bias1 = (const float*)d_in[13];
  const float* root2 = (const float*)d_in[14];
  const float* bias2 = (const float*)d_in[15];
  const float* fcW1  = (const float*)d_in[16];
  const float* fcb1  = (const float*)d_in[17];
  const float* fcW2  = (const float*)d_in[18];
  const float* fcb2  = (const float*)d_in[19];
  const float* fcW3  = (const float*)d_in[20];
  const float* fcb3  = (const float*)d_in[21];
  const float* fcW4  = (const float*)d_in[22];
  const float* fcb4  = (const float*)d_in[23];
  float* out = (float*)d_out;

  char* w = (char*)d_ws;
  size_t off = 0;
  auto take = [&](size_t bytes) -> void* {
    void* p = w + off;
    off = (off + bytes + 255) & ~(size_t)255;
    return p;
  };
  unsigned short* tabs = (unsigned short*)take(4 * 256 * 1024 * 2);
  unsigned short* w1p  = (unsigned short*)take((size_t)1024 * 1024 * 2 + 32768);
  unsigned short* w2p  = (unsigned short*)take((size_t)1024 * 2048 * 2 + 32768);
  float* agg1 = (float*)take((size_t)NV_N * 32 * 4);
  float* agg2 = (float*)take((size_t)NV_N * 64 * 4);
  int*   cnt  = (int*)take((size_t)NV_N * 4);
  float* h    = (float*)take((size_t)NV_N * 32 * 4);
  float* h2   = (float*)take((size_t)NV_N * 64 * 4);
  float* g    = (float*)take((size_t)NG_N * 64 * 4);
  float* l1   = (float*)take((size_t)NG_N * 512 * 4);
  float* l2   = (float*)take((size_t)NG_N * 512 * 4);
  float* l3   = (float*)take((size_t)NG_N * 256 * 4);

  hipMemsetAsync(agg1, 0, (size_t)NV_N * 32 * 4, stream);
  hipMemsetAsync(agg2, 0, (size_t)NV_N * 64 * 4, stream);
  hipMemsetAsync(cnt, 0, (size_t)NV_N * 4, stream);

  k_tables<<<4096, 256, 0, stream>>>(W1a, b1a, W2a, b2a, tabs);
  k_pack<<<(1024 * 1024 / 8 + 255) / 256, 256, 0, stream>>>(W1b, w1p, 1024);
  k_pack<<<(1024 * 2048 / 8 + 255) / 256, 256, 0, stream>>>(W2b, w2p, 2048);
  k_count<<<(E_N + 255) / 256, 256, 0, stream>>>(ei, cnt);

  const int nblk = (E_N + 127) / 128;
  k_edge<1024, 32><<<nblk, 256, 0, stream>>>(x, ei, eap, tabs, tabs + 262144,
                                             w1p, b1b, agg1);
  k_node1<<<(NV_N * 32) / 256, 256, 0, stream>>>(x, agg1, cnt, root1, bias1, h);

  k_edge<2048, 64><<<nblk, 256, 0, stream>>>(h, ei, eap, tabs + 2 * 262144, tabs + 3 * 262144,
                                             w2p, b2b, agg2);
  k_node2<<<(NV_N * 64) / 256, 256, 0, stream>>>(h, agg2, cnt, root2, bias2, h2);

  k_pool<<<(NG_N * 64) / 256, 256, 0, stream>>>(h2, batch, g);

  k_fc<64, true><<<dim3((NG_N + 7) / 8, 2), 256, 0, stream>>>(g, fcW1, fcb1, l1, 512);
  k_fc<512, true><<<dim3((NG_N + 7) / 8, 2), 256, 0, stream>>>(l1, fcW2, fcb2, l2, 512);
  k_fc<512, true><<<dim3((NG_N + 7) / 8, 1), 256, 0, stream>>>(l2, fcW3, fcb3, l3, 256);
  k_fc4<<<(NG_N * 4 + 255) / 256, 256, 0, stream>>>(l3, fcW4, fcb4, out);
}